// Round 8
// baseline (368.334 us; speedup 1.0000x reference)
//
#include <hip/hip_runtime.h>

// CubePad: x [N*6, C, 256, 256] f32 -> out [N*6, C, 258, 258] f32, pad=1.
// Face order: 0=front, 1=right, 2=back, 3=left, 4=top, 5=down.
// Single dispatch. blockIdx.x<9: bulk (8 pure quads/thread, no gather code).
// blockIdx.x==9: halo (the ~510 non-pure quads/plane via scalar gather).
// Quad partition: quad Q (flat elems 4Q..4Q+3 of the 66564-elem plane) is
// PURE iff start h in [1,256] and start w in [1,253] (then same-row, all
// interior). Non-pure quads = row-0 quads (0..64), row-257-region quads
// (16576..16640), and per row-junction r=2..256 the quad(s) containing flat
// 258r-1 and 258r. Proven complementary & duplicate-free.

#define C_  64
#define H_  256
#define W_  256
#define HP  258
#define WP  258
#define FACE_STRIDE (C_ * H_ * W_)     // 4,194,304
#define PLANE_IN  (H_ * W_)            // 65,536
#define PLANE_OUT (HP * WP)            // 66,564 (16B-divisible)
#define QP_PLANE  (PLANE_OUT / 4)      // 16,641 quads per plane
#define TOTAL_IN  (12 * FACE_STRIDE)   // 50,331,648 elements

typedef float f4  __attribute__((ext_vector_type(4)));              // 16B aligned
typedef float f4u __attribute__((ext_vector_type(4), aligned(4)));  // 4B aligned

__device__ __forceinline__ float value_at(const float* __restrict__ base,
                                          int face, int h, int w) {
#define IN(f, hh, ww) base[(size_t)(f) * FACE_STRIDE + (hh) * W_ + (ww)]
  if (h >= 1 && h <= H_ && w >= 1 && w <= W_) return IN(face, h - 1, w - 1);
  if (h == 0) {                       // top plate (corners via clamp)
    int wi = w - 1; wi = wi < 0 ? 0 : (wi > 255 ? 255 : wi);
    switch (face) {
      case 0:  return IN(4, 255, wi);
      case 1:  return IN(4, 255 - wi, 255);
      case 2:  return IN(4, 0, 255 - wi);
      case 3:  return IN(4, wi, 0);
      case 4:  return IN(2, 0, 255 - wi);
      default: return IN(0, 255, wi);
    }
  }
  if (h == HP - 1) {                  // bottom plate (corners via clamp)
    int wi = w - 1; wi = wi < 0 ? 0 : (wi > 255 ? 255 : wi);
    switch (face) {
      case 0:  return IN(5, 0, wi);
      case 1:  return IN(5, wi, 255);
      case 2:  return IN(5, 255, 255 - wi);
      case 3:  return IN(5, 255 - wi, 0);
      case 4:  return IN(0, 0, wi);
      default: return IN(2, 255, 255 - wi);
    }
  }
  int hi = h - 1;                     // h in [1,256]
  if (w == 0) {                       // left column
    switch (face) {
      case 0:  return IN(3, hi, 255);
      case 1:  return IN(0, hi, 255);
      case 2:  return IN(1, hi, 255);
      case 3:  return IN(2, hi, 255);
      case 4:  return IN(3, 0, hi);
      default: return IN(3, 255, 255 - hi);
    }
  }
  // right column (w == 257)
  switch (face) {
    case 0:  return IN(1, hi, 0);
    case 1:  return IN(2, hi, 0);
    case 2:  return IN(3, hi, 0);
    case 3:  return IN(0, hi, 0);
    case 4:  return IN(1, 0, 255 - hi);
    default: return IN(1, 255, hi);
  }
#undef IN
}

__global__ void cubepad_split_kernel(const float* __restrict__ x,
                                     float* __restrict__ out) {
  const int fgc = blockIdx.y;           // 0..767
  const int fg  = fgc >> 6;
  const int c   = fgc & 63;
  const int face = fg < 6 ? fg : fg - 6;
  const int nb   = fg < 6 ? 0 : 1;
  const int base_off = nb * 6 * FACE_STRIDE + c * PLANE_IN;
  const float* base = x + base_off;
  float* oplane = out + (size_t)fgc * PLANE_OUT;

  if (blockIdx.x < 9) {
    // ---------------- bulk: 8 quads per thread, no gathers ----------------
    const int q0 = blockIdx.x * 2048 + threadIdx.x;
    f4 v[8];
    unsigned hh[8], ww[8];
#pragma unroll
    for (int k = 0; k < 8; ++k) {
      const int q = q0 + (k << 8);
      const unsigned p = (unsigned)q << 2;
      const unsigned h = p / 258u;        // magic-div
      const unsigned w = p - h * 258u;
      hh[k] = h; ww[k] = w;
      int off = base_off + face * FACE_STRIDE + ((int)h - 1) * W_ + ((int)w - 1);
      off = off < 0 ? 0 : off;
      off = off > (TOTAL_IN - 4) ? (TOTAL_IN - 4) : off;
      v[k] = *(const f4u*)(x + off);      // unconditional clamped 16B load
    }
#pragma unroll
    for (int k = 0; k < 8; ++k) {
      const int q = q0 + (k << 8);
      const bool pure = (hh[k] >= 1u) & (hh[k] <= 256u) &
                        (ww[k] >= 1u) & (ww[k] <= 253u) & (q < QP_PLANE);
      if (pure) *(f4*)(oplane + ((size_t)q << 2)) = v[k];
    }
  } else {
    // ---------------- halo: non-pure quads via scalar gather --------------
    // slots: [0,65)   row-0 quads Q=j
    //        [65,130) row-257-region quads Q=16576+(j-65)
    //        [130,640) junctions r=2+(jj>>1), side=jj&1:
    //                  side0 Q=(258r-1)>>2; side1 (r even only) Q=(258r)>>2
    for (int it = 0; it < 3; ++it) {
      const int j = threadIdx.x + (it << 8);
      int Q = -1;
      if (j < 65) {
        Q = j;
      } else if (j < 130) {
        Q = 16576 + (j - 65);
      } else if (j < 640) {
        const int jj = j - 130;
        const int r = 2 + (jj >> 1);
        const int s = 258 * r;
        if ((jj & 1) == 0)       Q = (s - 1) >> 2;
        else if ((s & 3) == 0)   Q = s >> 2;      // r even: second quad
      }
      if (Q >= 0) {
        f4 v;
#pragma unroll
        for (int e = 0; e < 4; ++e) {
          const unsigned pe = ((unsigned)Q << 2) + e;
          const unsigned he = pe / 258u;
          const unsigned we = pe - he * 258u;
          v[e] = value_at(base, face, (int)he, (int)we);
        }
        *(f4*)(oplane + ((size_t)Q << 2)) = v;
      }
    }
  }
}

extern "C" void kernel_launch(void* const* d_in, const int* in_sizes, int n_in,
                              void* d_out, int out_size, void* d_ws, size_t ws_size,
                              hipStream_t stream) {
  const float* x = (const float*)d_in[0];
  float* out = (float*)d_out;
  dim3 grid(10, 768);   // x: 9 bulk blocks + 1 halo block per plane
  cubepad_split_kernel<<<grid, 256, 0, stream>>>(x, out);
}

// Round 10
// 338.988 us; speedup vs baseline: 1.0866x; 1.0866x over previous
//
#include <hip/hip_runtime.h>

// CubePad: x [N*6, C, 256, 256] f32 -> out [N*6, C, 258, 258] f32, pad=1.
// Face order: 0=front, 1=right, 2=back, 3=left, 4=top, 5=down.
// LDS-staged realignment: each block assembles 16 output rows in LDS
// (aligned float4 global loads for the interior; scalar value_at gathers for
// the border cells), then streams them out as dense ALIGNED float4 stores.
// Block slabs are 16512B = 129 x 128B: disjoint at cache-line granularity.

#define C_  64
#define H_  256
#define W_  256
#define HP  258
#define WP  258
#define FACE_STRIDE (C_ * H_ * W_)     // 4,194,304
#define PLANE_IN  (H_ * W_)            // 65,536
#define PLANE_OUT (HP * WP)            // 66,564
#define RPB 16                         // rows per block (last block: 2)

typedef float f4 __attribute__((ext_vector_type(4)));   // 16B aligned

__device__ __forceinline__ float value_at(const float* __restrict__ base,
                                          int face, int h, int w) {
#define IN(f, hh, ww) base[(size_t)(f) * FACE_STRIDE + (hh) * W_ + (ww)]
  if (h >= 1 && h <= H_ && w >= 1 && w <= W_) return IN(face, h - 1, w - 1);
  if (h == 0) {                       // top plate (corners via clamp)
    int wi = w - 1; wi = wi < 0 ? 0 : (wi > 255 ? 255 : wi);
    switch (face) {
      case 0:  return IN(4, 255, wi);
      case 1:  return IN(4, 255 - wi, 255);
      case 2:  return IN(4, 0, 255 - wi);
      case 3:  return IN(4, wi, 0);
      case 4:  return IN(2, 0, 255 - wi);
      default: return IN(0, 255, wi);
    }
  }
  if (h == HP - 1) {                  // bottom plate (corners via clamp)
    int wi = w - 1; wi = wi < 0 ? 0 : (wi > 255 ? 255 : wi);
    switch (face) {
      case 0:  return IN(5, 0, wi);
      case 1:  return IN(5, wi, 255);
      case 2:  return IN(5, 255, 255 - wi);
      case 3:  return IN(5, 255 - wi, 0);
      case 4:  return IN(0, 0, wi);
      default: return IN(2, 255, 255 - wi);
    }
  }
  int hi = h - 1;                     // h in [1,256]
  if (w == 0) {                       // left column
    switch (face) {
      case 0:  return IN(3, hi, 255);
      case 1:  return IN(0, hi, 255);
      case 2:  return IN(1, hi, 255);
      case 3:  return IN(2, hi, 255);
      case 4:  return IN(3, 0, hi);
      default: return IN(3, 255, 255 - hi);
    }
  }
  // right column (w == 257)
  switch (face) {
    case 0:  return IN(1, hi, 0);
    case 1:  return IN(2, hi, 0);
    case 2:  return IN(3, hi, 0);
    case 3:  return IN(0, hi, 0);
    case 4:  return IN(1, 0, 255 - hi);
    default: return IN(1, 255, hi);
  }
#undef IN
}

__global__ __launch_bounds__(256) void cubepad_lds_kernel(
    const float* __restrict__ x, float* __restrict__ out) {
  __shared__ float lds[RPB * WP];       // 16*258 floats = 16512 B
  const int t   = threadIdx.x;          // 0..255
  const int fgc = blockIdx.y;           // 0..767
  const int fg  = fgc >> 6;
  const int c   = fgc & 63;
  const int face = fg < 6 ? fg : fg - 6;
  const int nb   = fg < 6 ? 0 : 1;
  const float* base = x + (size_t)(nb * 6) * FACE_STRIDE + (size_t)c * PLANE_IN;

  const int h0    = blockIdx.x * RPB;   // 0,16,...,256
  const int nrows = (h0 == 256) ? 2 : RPB;

  // ---- A1: interior rows, aligned float4 loads -> LDS (shifted +1 col) ----
#pragma unroll
  for (int j = 0; j < 4; ++j) {
    const int idx = t + (j << 8);       // 0..1023
    const int r   = idx >> 6;           // row_local 0..15
    const int qw  = idx & 63;           // quad within input row
    const int h   = h0 + r;
    if (r < nrows && h >= 1 && h <= 256) {
      const float* src = base + (size_t)face * FACE_STRIDE +
                         (size_t)(h - 1) * W_ + (qw << 2);
      f4 v = *(const f4*)src;           // aligned 16B load
      float* dst = &lds[r * WP + 1 + (qw << 2)];
      dst[0] = v.x; dst[1] = v.y; dst[2] = v.z; dst[3] = v.w;
    }
  }
  // ---- A2: left/right border cells of interior rows ----
  if (t < 2 * RPB) {
    const int r = t >> 1, side = t & 1;
    const int h = h0 + r;
    if (r < nrows && h >= 1 && h <= 256) {
      const int w = side ? 257 : 0;
      lds[r * WP + w] = value_at(base, face, h, w);
    }
  }
  // ---- A2b: full gather rows (row 0 in block 0; row 257 in last block) ----
  if (h0 == 0) {
    for (int w = t; w < WP; w += 256) lds[w] = value_at(base, face, 0, w);
  }
  if (h0 == 256) {
    for (int w = t; w < WP; w += 256) lds[WP + w] = value_at(base, face, 257, w);
  }
  __syncthreads();

  // ---- B: dense aligned float4 copy LDS -> out ----
  const int nq = (nrows * WP) >> 2;     // 1032 (or 129 for last block)
  f4* oq = (f4*)(out + (size_t)fgc * PLANE_OUT + (size_t)h0 * WP);
  const f4* lq = (const f4*)lds;
  for (int qi = t; qi < nq; qi += 256) oq[qi] = lq[qi];
}

extern "C" void kernel_launch(void* const* d_in, const int* in_sizes, int n_in,
                              void* d_out, int out_size, void* d_ws, size_t ws_size,
                              hipStream_t stream) {
  const float* x = (const float*)d_in[0];
  float* out = (float*)d_out;
  dim3 grid(17, 768);   // 16 full strips + 1 two-row strip, per plane
  cubepad_lds_kernel<<<grid, 256, 0, stream>>>(x, out);
}